// Round 1
// baseline (1083.573 us; speedup 1.0000x reference)
//
#include <hip/hip_runtime.h>

// dictloss: ss_b = D@X + meanY; overlap-add over stride-1 patches; masked blend; A@v; MSE.
// Key identity: patches[p,k]=k+p  =>  ss_p_sum[n] = sum_a sum_p d[p,a]*x[a,n-p]  (FIR bank)
// plus meanY*npp[n] (npp given as input).

namespace {
constexpr int kP = 64;        // patch size
constexpr int kA = 256;       // atoms
constexpr int kN = 262144;    // signal length
constexpr int kK = 262081;    // npatches
constexpr int kM = 512;       // rows of A

// ---- conv kernel geometry ----
constexpr int CB = 256;             // threads per block
constexpr int OPT = 16;             // outputs per thread
constexpr int NB = CB * OPT;        // 4096 outputs per block
constexpr int NCHUNK = kN / NB;     // 64
constexpr int NSPLIT = 8;           // atom splits
constexpr int APS = kA / NSPLIT;    // 32 atoms per block
constexpr int XS_LOG = NB + 64;     // 4160 logical staged floats (k in [n0-63, n0+NB])
constexpr int XS_L4 = XS_LOG / 4;   // 1040 logical float4
constexpr int XS_P4 = 1304;         // skewed physical float4 count (1299 needed + pad)
constexpr int R4 = XS_L4 + 1;       // 1041 staging float4 rounds
constexpr int GV_CH = 8;            // gemv column chunks per row

__device__ __forceinline__ float f4c(const float4& v, int i) {
  switch (i & 3) {
    case 0: return v.x;
    case 1: return v.y;
    case 2: return v.z;
    default: return v.w;
  }
}

// Stage x[a, n0-63 .. n0+NB] into LDS (zero-padded outside [0,kK)), with
// +4-float skew every 16 floats: phys(i) = i + 4*(i>>4)  (keeps float4s intact,
// makes the stride-16 window reads bank-conflict-free).
// Alignment: (a*kK + n0 - 63) mod 4 == (a+1)&3 since kK%4==1, n0%4==0.
__device__ __forceinline__ void stage_row(const float* __restrict__ x,
                                          float* __restrict__ xsf,
                                          int a, int n0) {
  const int SA = (a + 1) & 3;
  const int gf = a * kK + n0 - 63 - SA;     // 16B-aligned float index (can be <0)
  const int g4base = gf >> 2;
  const float4* __restrict__ x4 = (const float4*)x;
  const int g4max = (kA * kK) / 4 - 1;
  for (int r = threadIdx.x; r < R4; r += CB) {
    int g4 = g4base + r;
    g4 = g4 < 0 ? 0 : (g4 > g4max ? g4max : g4);   // mem-safe; OOB values zeroed below
    float4 val = x4[g4];
#pragma unroll
    for (int w = 0; w < 4; ++w) {
      int i = 4 * r + w - SA;                      // logical index
      if ((unsigned)i < (unsigned)XS_LOG) {
        int k = n0 - 63 + i;
        float f = ((unsigned)k < (unsigned)kK) ? f4c(val, w) : 0.0f;
        xsf[i + 4 * (i >> 4)] = f;
      }
    }
  }
}

// acc[j] (j=0..15) += sum_q d[63-q] * xs[tid*16 + j + q], q = 0..63.
// Rolling 5-float4 register window; all indices compile-time after full unroll.
__device__ __forceinline__ void compute_atom(const float4* __restrict__ xs4,
                                             const float4* __restrict__ dt4,
                                             int a_loc, float* __restrict__ acc) {
  const int t4 = threadIdx.x * 4;
  float4 w[5];
#pragma unroll
  for (int q = 0; q < 4; ++q) {
    int l4 = t4 + q;
    w[q] = xs4[l4 + (l4 >> 2)];                    // phys4 = l4 + l4/4 (exact: t4%4==0)
  }
#pragma unroll
  for (int c = 0; c < 16; ++c) {
    {
      int l4 = t4 + c + 4;
      w[(c + 4) % 5] = xs4[l4 + (l4 >> 2)];
    }
    float4 D = dt4[a_loc * 16 + 15 - c];           // dT[p=60-4c .. 63-4c]
    float dc[4] = {D.w, D.z, D.y, D.x};            // dc[i] = d[63-4c-i] = coef for q=4c+i
#pragma unroll
    for (int i = 0; i < 4; ++i) {
      float coef = dc[i];
#pragma unroll
      for (int j = 0; j < OPT; ++j) {
        int off = i + j;                           // 0..18
        float xv = f4c(w[(c + (off >> 2)) % 5], off & 3);
        acc[j] = fmaf(coef, xv, acc[j]);
      }
    }
  }
}

__global__ __launch_bounds__(CB, 2) void conv_kernel(const float* __restrict__ d,
                                                     const float* __restrict__ x,
                                                     float* __restrict__ sum) {
  __shared__ float4 xsA[XS_P4];
  __shared__ float4 xsB[XS_P4];
  __shared__ float4 dt4[APS * 16];                 // dT[a_loc][p], row stride 64 floats
  const int n0 = blockIdx.x * NB;
  const int a0 = blockIdx.y * APS;
  const int tid = threadIdx.x;

  // one-time: transpose this block's d columns into LDS
  float* dtf = (float*)dt4;
#pragma unroll 1
  for (int i = tid; i < APS * kP; i += CB) {
    int al = i & (APS - 1);
    int p = i >> 5;                                // APS == 32
    dtf[al * kP + p] = d[p * kA + a0 + al];
  }

  float acc[OPT];
#pragma unroll
  for (int j = 0; j < OPT; ++j) acc[j] = 0.0f;

  stage_row(x, (float*)xsA, a0, n0);
  __syncthreads();

#pragma unroll 1
  for (int a = 0; a < APS; a += 2) {               // double-buffered: 1 barrier per atom
    stage_row(x, (float*)xsB, a0 + a + 1, n0);
    compute_atom(xsA, dt4, a, acc);
    __syncthreads();
    if (a + 2 < APS) stage_row(x, (float*)xsA, a0 + a + 2, n0);
    compute_atom(xsB, dt4, a + 1, acc);
    __syncthreads();
  }

  const int nb = n0 + tid * OPT;
#pragma unroll
  for (int j = 0; j < OPT; ++j) atomicAdd(sum + nb + j, acc[j]);
}

__global__ void zero_kernel(float* __restrict__ sum, float* __restrict__ Tref) {
  const int i = blockIdx.x * blockDim.x + threadIdx.x;   // float4 index over kN/4
  ((float4*)sum)[i] = make_float4(0.f, 0.f, 0.f, 0.f);
  if (i < kM / 4) ((float4*)Tref)[i] = make_float4(0.f, 0.f, 0.f, 0.f);
}

__global__ void vmask_kernel(const float* __restrict__ sum, const float* __restrict__ ds,
                             const float* __restrict__ npp, const float* __restrict__ vb,
                             const float* __restrict__ sRef,
                             const float* __restrict__ pMeanY,
                             const float* __restrict__ pLam2, float* __restrict__ v) {
  const int i = blockIdx.x * blockDim.x + threadIdx.x;   // float4 index over kN/4
  const float meanY = pMeanY[0];
  const float lam2 = pLam2[0];
  const float4 s = ((const float4*)sum)[i];
  const float4 dd = ((const float4*)ds)[i];
  const float4 np = ((const float4*)npp)[i];
  const float4 vbv = ((const float4*)vb)[i];
  const float4 sr = ((const float4*)sRef)[i];
  float4 r;
  r.x = (lam2 * dd.x + s.x + meanY * np.x) / (lam2 + np.x) * vbv.x + sr.x;
  r.y = (lam2 * dd.y + s.y + meanY * np.y) / (lam2 + np.y) * vbv.y + sr.y;
  r.z = (lam2 * dd.z + s.z + meanY * np.z) / (lam2 + np.z) * vbv.z + sr.z;
  r.w = (lam2 * dd.w + s.w + meanY * np.w) / (lam2 + np.w) * vbv.w + sr.w;
  ((float4*)v)[i] = r;
}

__global__ __launch_bounds__(256) void gemv_kernel(const float* __restrict__ A,
                                                   const float* __restrict__ v,
                                                   float* __restrict__ Tref) {
  const int m = blockIdx.x >> 3;                   // GV_CH == 8
  const int ch = blockIdx.x & (GV_CH - 1);
  const float4* __restrict__ A4 = (const float4*)(A + (size_t)m * kN);
  const float4* __restrict__ v4 = (const float4*)v;
  const int b0 = ch * (kN / 4 / GV_CH) + threadIdx.x;
  float s = 0.0f;
#pragma unroll 8
  for (int r = 0; r < 32; ++r) {
    float4 av = A4[b0 + r * 256];
    float4 vv = v4[b0 + r * 256];
    s = fmaf(av.x, vv.x, s);
    s = fmaf(av.y, vv.y, s);
    s = fmaf(av.z, vv.z, s);
    s = fmaf(av.w, vv.w, s);
  }
#pragma unroll
  for (int o = 32; o > 0; o >>= 1) s += __shfl_down(s, o, 64);
  if ((threadIdx.x & 63) == 0) atomicAdd(Tref + m, s);
}

__global__ void loss_kernel(const float* __restrict__ Tref, const float* __restrict__ Tarr,
                            float* __restrict__ out) {
  const int tid = threadIdx.x;
  float s = 0.0f;
  for (int i = tid; i < kM; i += 256) {
    float df = Tref[i] - Tarr[i];
    s = fmaf(df, df, s);
  }
#pragma unroll
  for (int o = 32; o > 0; o >>= 1) s += __shfl_down(s, o, 64);
  __shared__ float red[4];
  if ((tid & 63) == 0) red[tid >> 6] = s;
  __syncthreads();
  if (tid == 0) out[0] = (red[0] + red[1] + red[2] + red[3]) * (1.0f / kM);
}

}  // namespace

extern "C" void kernel_launch(void* const* d_in, const int* in_sizes, int n_in,
                              void* d_out, int out_size, void* d_ws, size_t ws_size,
                              hipStream_t stream) {
  const float* d    = (const float*)d_in[0];   // [1,64,256]
  const float* x    = (const float*)d_in[1];   // [256, 262081]
  const float* vb   = (const float*)d_in[3];   // [N,1]
  const float* npp  = (const float*)d_in[5];   // [N,1]
  const float* sRef = (const float*)d_in[6];   // [N,1]
  const float* A    = (const float*)d_in[7];   // [512, N]
  const float* Tarr = (const float*)d_in[8];   // [512,1]
  const float* pMeanY = (const float*)d_in[9];
  const float* ds   = (const float*)d_in[10];
  const float* pLam2 = (const float*)d_in[11];
  float* out = (float*)d_out;

  // workspace layout (floats): sum[kN] | v[kN] | Tref[kM]   (~2.1 MB, all 16B-aligned)
  float* sum  = (float*)d_ws;
  float* v    = sum + kN;
  float* Tref = v + kN;

  zero_kernel<<<kN / 4 / 256, 256, 0, stream>>>(sum, Tref);
  conv_kernel<<<dim3(NCHUNK, NSPLIT), CB, 0, stream>>>(d, x, sum);
  vmask_kernel<<<kN / 4 / 256, 256, 0, stream>>>(sum, ds, npp, vb, sRef, pMeanY, pLam2, v);
  gemv_kernel<<<kM * GV_CH, 256, 0, stream>>>(A, v, Tref);
  loss_kernel<<<1, 256, 0, stream>>>(Tref, Tarr, out);
}